// Round 9
// baseline (198.678 us; speedup 1.0000x reference)
//
#include <hip/hip_runtime.h>

// ---------------------------------------------------------------------------
// Fused: qkv-proj + head-LN -> cross-attention (x2) -> proj.
// B=4, N=1024, C=768, H=12, HD=64.  MFMA bf16 16x16x32, f32 accum.
//
// Round-9:
//  * fragment-tiled bf16 layout (1KB coalesced wave loads) everywhere.
//  * GEMM: r7-measured-best mainloop (__syncthreads, single-buffer LDS,
//    BK=64, reg prefetch distance 1).  r8's raw lgkm barriers REGRESSED
//    (asm memory clobber defeats backend prefetch scheduling) -- reverted.
//  * Attention: K/V double-buffered LDS -> ONE __syncthreads per key-tile
//    (store targets the buffer whose readers passed the previous sync).
//  * V-transpose fused into gemm_qkv epilogue (no k_vt kernel).
//  * XCD-aware grids: gemm x=m-tile (same-A co-XCD); attn x=head-instance
//    (per-head K/V L2-hot, 3MB/XCD).
//
// ws layout (ushort elements):
//   xbt  @ 0        : tiled [8192 x 768]  (rows 0..4095 before, rest after)
//   wqt  @ 6291456  : tiled [2304 x 768]
//   wpt  @ 8060928  : tiled [768 x 768]
//   qkvr @ 8650752  : tiled [8192 x 1536] post-LN q,k (192 k-chunks)
//   vtg  @ 21233664 : 96 heads x tiled [64 d x 1024 key]
//   ctx  @ 27525120 : tiled [8192 x 768]
// ---------------------------------------------------------------------------

typedef __bf16 bf16x8 __attribute__((ext_vector_type(8)));
typedef float  f32x4  __attribute__((ext_vector_type(4)));
typedef unsigned int u32x4 __attribute__((ext_vector_type(4)));
typedef unsigned short us;

#define MFMA16(a, b, c) __builtin_amdgcn_mfma_f32_16x16x32_bf16(a, b, c, 0, 0, 0)

__device__ __forceinline__ us f2bf(float f) {
  unsigned int u = __builtin_bit_cast(unsigned int, f);
  u += 0x7FFFu + ((u >> 16) & 1u);   // RNE
  return (us)(u >> 16);
}
__device__ __forceinline__ float bf2f(us h) {
  unsigned int u = ((unsigned int)h) << 16;
  return __builtin_bit_cast(float, u);
}
__device__ __forceinline__ bf16x8 ld16(const us* p) {
  return __builtin_bit_cast(bf16x8, *(const u32x4*)p);
}

// LDS chunk stride: 128 elems payload padded to 136 (272B; 68 words ≡ 4
// mod 32 -> quad-adjacent chunks hit shifted banks).
#define CH 136

// ---------------------------------------------------------------- convert --
// f32 row-major -> bf16 fragment-tiled.  One 16B tiled piece per thread.
__global__ __launch_bounds__(256) void k_convert(
    const float* __restrict__ before, const float* __restrict__ after,
    const float* __restrict__ wqkv, const float* __restrict__ wproj,
    us* __restrict__ ws) {
  int t = blockIdx.x * 256 + threadIdx.x;
  us* dst; int u;
  if (t < 786432)       { u = t;           dst = ws; }
  else if (t < 1007616) { u = t - 786432;  dst = ws + 6291456; }
  else                  { u = t - 1007616; dst = ws + 8060928; }
  int l15 = u & 15, c2 = u >> 4;
  int kc = c2 % 96, mt = c2 / 96;
  int row = mt * 16 + l15;
  const float* srow;
  if (t < 786432)       srow = row < 4096 ? before + (size_t)row * 768
                                          : after + (size_t)(row - 4096) * 768;
  else if (t < 1007616) srow = wqkv + (size_t)row * 768;
  else                  srow = wproj + (size_t)row * 768;
  const float4* s4 = (const float4*)(srow + kc * 8);
  float4 a = s4[0], b = s4[1];
  union { u32x4 v; us s[8]; } o;
  o.s[0] = f2bf(a.x); o.s[1] = f2bf(a.y); o.s[2] = f2bf(a.z); o.s[3] = f2bf(a.w);
  o.s[4] = f2bf(b.x); o.s[5] = f2bf(b.y); o.s[6] = f2bf(b.z); o.s[7] = f2bf(b.w);
  *(u32x4*)(dst + (size_t)c2 * 128 + l15 * 8) = o.v;
}

// -------------------------------------------------------------- gemm main --
// NT GEMM main loop on tiled operands, block tile MT x 128, 4 waves (2x2),
// K=768 (12 x BK=64).  r7 structure: single-buffer LDS, __syncthreads,
// reg prefetch distance 1.
template <int MT>
__device__ __forceinline__ void gemm_mainloop(
    const us* __restrict__ A, const us* __restrict__ B,
    int m0, int n0, us* As, us* Bs, f32x4 (&acc)[MT / 32][4]) {
  constexpr int AJ = MT / 32;
  constexpr int NITER = 12;
  const int tid = threadIdx.x, lane = tid & 63, w = tid >> 6;
  const int quad = lane >> 4, l15 = lane & 15;
  const int wm = (w >> 1) * (MT / 2), wn = (w & 1) * 64;
  u32x4 ra[AJ], rb[4];

  auto load_regs = [&](int k0) {
#pragma unroll
    for (int j = 0; j < AJ; ++j) {
      int u = w * AJ + j;
      ra[j] = *(const u32x4*)(A + ((size_t)((m0 >> 4) + (u >> 1)) * 96
                                   + (k0 >> 3) + (u & 1) * 4) * 128 + lane * 8);
    }
#pragma unroll
    for (int j = 0; j < 4; ++j) {
      int u = w * 4 + j;
      rb[j] = *(const u32x4*)(B + ((size_t)((n0 >> 4) + (u >> 1)) * 96
                                   + (k0 >> 3) + (u & 1) * 4) * 128 + lane * 8);
    }
  };
  auto store_regs = [&]() {
#pragma unroll
    for (int j = 0; j < AJ; ++j) {
      int slot = (w * AJ + j) * 4 + quad;
      *(u32x4*)(As + slot * CH + l15 * 8) = ra[j];
    }
#pragma unroll
    for (int j = 0; j < 4; ++j) {
      int slot = (w * 4 + j) * 4 + quad;
      *(u32x4*)(Bs + slot * CH + l15 * 8) = rb[j];
    }
  };

  load_regs(0);
  store_regs();
  __syncthreads();

#pragma unroll
  for (int it = 0; it < NITER; ++it) {
    if (it + 1 < NITER) load_regs((it + 1) * 64);
#pragma unroll
    for (int ks = 0; ks < 2; ++ks) {
      bf16x8 af[AJ], bfr[4];
#pragma unroll
      for (int mf = 0; mf < AJ; ++mf)
        af[mf] = ld16(As + (((wm >> 4) + mf) * 8 + ks * 4 + quad) * CH + l15 * 8);
#pragma unroll
      for (int nf = 0; nf < 4; ++nf)
        bfr[nf] = ld16(Bs + (((wn >> 4) + nf) * 8 + ks * 4 + quad) * CH + l15 * 8);
#pragma unroll
      for (int mf = 0; mf < AJ; ++mf)
#pragma unroll
        for (int nf = 0; nf < 4; ++nf)
          acc[mf][nf] = MFMA16(af[mf], bfr[nf], acc[mf][nf]);
    }
    __syncthreads();
    if (it + 1 < NITER) {
      store_regs();
      __syncthreads();
    }
  }
}

// --------------------------------------------------------------- gemm qkv --
// grid (64 m-tiles, 18 n-tiles); XCD = m%8 (same-A co-XCD).  Per-head LN
// epilogue.  cols < 1536 -> tiled qkvr (192 chunks); cols >= 1536 (v) ->
// TRANSPOSED tiled vtg (fused k_vt).
__global__ __launch_bounds__(256) void k_gemm_qkv(
    const us* __restrict__ A, const us* __restrict__ B, us* __restrict__ Cqk,
    us* __restrict__ Vg, const float* __restrict__ g, const float* __restrict__ bb) {
  __shared__ us As[64 * CH];
  __shared__ us Bs[64 * CH];
  const int lane = threadIdx.x & 63, w = threadIdx.x >> 6;
  const int quad = lane >> 4, l15 = lane & 15;
  const int m0 = blockIdx.x * 128, n0 = blockIdx.y * 128;
  const int wm = (w >> 1) * 64, wn = (w & 1) * 64;
  f32x4 acc[4][4] = {};
  gemm_mainloop<128>(A, B, m0, n0, As, Bs, acc);

  float gl[4], bl[4];
#pragma unroll
  for (int nf = 0; nf < 4; ++nf) { gl[nf] = g[nf * 16 + l15]; bl[nf] = bb[nf * 16 + l15]; }

  if ((n0 + wn) < 1536) {
    // q/k -> tiled qkvr (192 k-chunks)
#pragma unroll
    for (int mf = 0; mf < 4; ++mf)
#pragma unroll
      for (int r = 0; r < 4; ++r) {
        float s1 = acc[mf][0][r] + acc[mf][1][r] + acc[mf][2][r] + acc[mf][3][r];
        float s2 = acc[mf][0][r] * acc[mf][0][r] + acc[mf][1][r] * acc[mf][1][r]
                 + acc[mf][2][r] * acc[mf][2][r] + acc[mf][3][r] * acc[mf][3][r];
#pragma unroll
        for (int o = 1; o < 16; o <<= 1) { s1 += __shfl_xor(s1, o); s2 += __shfl_xor(s2, o); }
        float mu = s1 * (1.0f / 64.0f);
        float var = s2 * (1.0f / 64.0f) - mu * mu;
        float sc = rsqrtf(var + 1e-5f);
        size_t cb = ((size_t)(((m0 + wm) >> 4) + mf) * 192 + ((n0 + wn) >> 3)
                     + (l15 >> 3)) * 128 + (quad * 4 + r) * 8 + (l15 & 7);
#pragma unroll
        for (int nf = 0; nf < 4; ++nf)
          Cqk[cb + nf * 256] = f2bf((acc[mf][nf][r] - mu) * sc * gl[nf] + bl[nf]);
      }
  } else {
    // v -> transposed tiled vtg[hi][d][key]
    const int h = ((n0 + wn) - 1536) >> 6;
#pragma unroll
    for (int mf = 0; mf < 4; ++mf) {
      int mrow = m0 + wm + mf * 16;        // 16-aligned
      int s = mrow >> 12, b2 = (mrow >> 10) & 3;
      int K0 = mrow & 1023;
      us* vb = Vg + (size_t)(s * 48 + b2 * 12 + h) * 65536;
      float vv[4][4];
#pragma unroll
      for (int r = 0; r < 4; ++r) {
        float s1 = acc[mf][0][r] + acc[mf][1][r] + acc[mf][2][r] + acc[mf][3][r];
        float s2 = acc[mf][0][r] * acc[mf][0][r] + acc[mf][1][r] * acc[mf][1][r]
                 + acc[mf][2][r] * acc[mf][2][r] + acc[mf][3][r] * acc[mf][3][r];
#pragma unroll
        for (int o = 1; o < 16; o <<= 1) { s1 += __shfl_xor(s1, o); s2 += __shfl_xor(s2, o); }
        float mu = s1 * (1.0f / 64.0f);
        float var = s2 * (1.0f / 64.0f) - mu * mu;
        float sc = rsqrtf(var + 1e-5f);
#pragma unroll
        for (int nf = 0; nf < 4; ++nf)
          vv[nf][r] = (acc[mf][nf][r] - mu) * sc * gl[nf] + bl[nf];
      }
#pragma unroll
      for (int nf = 0; nf < 4; ++nf) {
        ushort4 o4;
        o4.x = f2bf(vv[nf][0]); o4.y = f2bf(vv[nf][1]);
        o4.z = f2bf(vv[nf][2]); o4.w = f2bf(vv[nf][3]);
        *(ushort4*)(vb + ((size_t)nf * 128 + (K0 >> 3) + (quad >> 1)) * 128
                    + l15 * 8 + (quad & 1) * 4) = o4;
      }
    }
  }
}

// -------------------------------------------------------------- gemm proj --
// grid (128 m-tiles, 6 n-tiles).  f32 row-major out + bias + untransposed-q
// residual (from tiled qkvr, 192 chunks).
__global__ __launch_bounds__(256) void k_gemm_proj(
    const us* __restrict__ A, const us* __restrict__ B, float* __restrict__ C,
    const us* __restrict__ qkvr, const float* __restrict__ bias) {
  __shared__ us As[32 * CH];
  __shared__ us Bs[64 * CH];
  const int lane = threadIdx.x & 63, w = threadIdx.x >> 6;
  const int quad = lane >> 4, l15 = lane & 15;
  const int m0 = blockIdx.x * 64, n0 = blockIdx.y * 128;
  const int wm = (w >> 1) * 32, wn = (w & 1) * 64;
  f32x4 acc[2][4] = {};
  gemm_mainloop<64>(A, B, m0, n0, As, Bs, acc);

  const int cg = (n0 + wn) >> 6;          // wave-uniform column group
  float bl[4];
#pragma unroll
  for (int nf = 0; nf < 4; ++nf) bl[nf] = bias[n0 + wn + nf * 16 + l15];
#pragma unroll
  for (int mf = 0; mf < 2; ++mf)
#pragma unroll
    for (int r = 0; r < 4; ++r) {
      int row = m0 + wm + mf * 16 + quad * 4 + r;
      int hf = row >> 12;                 // 0 -> context_b (q=after), 1 -> context_a
      int m4 = row & 4095;
      int b = m4 >> 10, i = m4 & 1023;
      int j = i * 12 + cg;                // f>>6 where f = i*768+col
      int h = j >> 10, n = j & 1023;      // d = nf*16 + l15
      int qrow = ((hf ^ 1) << 12) + (b << 10) + n;
      size_t rb2 = ((size_t)(qrow >> 4) * 192 + h * 8 + (l15 >> 3)) * 128
                 + (qrow & 15) * 8 + (l15 & 7);
      size_t base = (size_t)row * 768 + n0 + wn + l15;
#pragma unroll
      for (int nf = 0; nf < 4; ++nf)
        C[base + nf * 16] = acc[mf][nf][r] + bl[nf] + bf2f(qkvr[rb2 + nf * 256]);
    }
}

// -------------------------------------------------------------- attention --
// grid (96 hi, 8 qt) -> XCD = hi%8 (per-head K/V L2-hot).  K/V double-
// buffered in LDS -> ONE __syncthreads per key-tile: store targets buf p^1,
// whose readers all passed the previous sync.  Static-max softmax (LN'd
// q,k), deferred l-reduction.
__global__ __launch_bounds__(256) void k_attn(const us* __restrict__ qkvr,
                                              const us* __restrict__ vtg,
                                              us* __restrict__ ctx) {
  __shared__ us Ks[2][32 * CH];
  __shared__ us Vt[2][32 * CH];
  __shared__ us Ps[4][32 * 72];
  const int tid = threadIdx.x, lane = tid & 63, w = tid >> 6;
  const int quad = lane >> 4, l15 = lane & 15;
  const int hi = blockIdx.x, qt = blockIdx.y;
  const int hf = hi / 48, bh = hi - hf * 48;
  const int b = bh / 12, h = bh - (bh / 12) * 12;
  const int ihq = hf ^ 1, ihk = hf;
  const int r0 = qt * 128 + w * 32;
  const int qmt = (ihq * 4096 + b * 1024 + r0) >> 4;
  const int kb16 = (ihk * 4096 + b * 1024) >> 4;
  const us* vbase = vtg + (size_t)(ihk * 48 + b * 12 + h) * 65536;
  const float c1 = 0.125f * 1.44269504088896340736f;  // scale * log2(e)

  // Q fragments resident (A-layout), direct from tiled global
  bf16x8 aq[2][2];
#pragma unroll
  for (int mf = 0; mf < 2; ++mf)
#pragma unroll
    for (int ks = 0; ks < 2; ++ks)
      aq[mf][ks] = ld16(qkvr + ((size_t)(qmt + mf) * 192 + h * 8 + ks * 4 + quad) * 128
                        + l15 * 8);

  u32x4 rk[2], rv[2];
  auto load_kv = [&](int kt) {
#pragma unroll
    for (int j = 0; j < 2; ++j) {
      int u = w * 2 + j;
      rk[j] = *(const u32x4*)(qkvr + ((size_t)(kb16 + kt * 4 + (u >> 1)) * 192
                                      + 96 + h * 8 + (u & 1) * 4) * 128 + lane * 8);
      rv[j] = *(const u32x4*)(vbase + ((size_t)(u >> 1) * 128 + kt * 8
                                       + (u & 1) * 4) * 128 + lane * 8);
    }
  };
  auto store_kv = [&](int buf) {
#pragma unroll
    for (int j = 0; j < 2; ++j) {
      int slot = (w * 2 + j) * 4 + quad;
      *(u32x4*)(Ks[buf] + slot * CH + l15 * 8) = rk[j];
      *(u32x4*)(Vt[buf] + slot * CH + l15 * 8) = rv[j];
    }
  };

  f32x4 O[2][4] = {};
  float lsum[2][4] = {};
  us* myP = Ps[w];

  load_kv(0);
  store_kv(0);
  __syncthreads();

  for (int kt = 0; kt < 16; ++kt) {
    const int p = kt & 1;
    if (kt + 1 < 16) load_kv(kt + 1);

    // S = Q K^T
    f32x4 s[2][4] = {};
#pragma unroll
    for (int ks = 0; ks < 2; ++ks)
#pragma unroll
      for (int nf = 0; nf < 4; ++nf) {
        bf16x8 bk = ld16(Ks[p] + (nf * 8 + ks * 4 + quad) * CH + l15 * 8);
        s[0][nf] = MFMA16(aq[0][ks], bk, s[0][nf]);
        s[1][nf] = MFMA16(aq[1][ks], bk, s[1][nf]);
      }

    // static-max softmax; per-lane partial l sums
#pragma unroll
    for (int mf = 0; mf < 2; ++mf)
#pragma unroll
      for (int r = 0; r < 4; ++r) {
        float p0 = __builtin_amdgcn_exp2f(s[mf][0][r] * c1);
        float p1 = __builtin_amdgcn_exp2f(s[mf][1][r] * c1);
        float p2 = __builtin_amdgcn_exp2f(s[mf][2][r] * c1);
        float p3 = __builtin_amdgcn_exp2f(s[mf][3][r] * c1);
        lsum[mf][r] += (p0 + p1) + (p2 + p3);
        int rowq = (mf * 16 + quad * 4 + r) * 72 + l15;
        myP[rowq]      = f2bf(p0);
        myP[rowq + 16] = f2bf(p1);
        myP[rowq + 32] = f2bf(p2);
        myP[rowq + 48] = f2bf(p3);
      }

    // O += P V   (per-wave LDS round-trip)
#pragma unroll
    for (int k2 = 0; k2 < 2; ++k2) {
      bf16x8 pa0 = ld16(myP + l15 * 72 + k2 * 32 + quad * 8);
      bf16x8 pa1 = ld16(myP + (16 + l15) * 72 + k2 * 32 + quad * 8);
#pragma unroll
      for (int df = 0; df < 4; ++df) {
        bf16x8 bv = ld16(Vt[p] + (df * 8 + k2 * 4 + quad) * CH + l15 * 8);
        O[0][df] = MFMA16(pa0, bv, O[0][df]);
        O[1][df] = MFMA16(pa1, bv, O[1][df]);
      }
    }

    if (kt + 1 < 16) store_kv(p ^ 1);
    __syncthreads();
  }

  // epilogue: l-reduction, scale, store ctx TILED (96 k-chunks)
  const int omt = (hf * 4096 + b * 1024 + r0) >> 4;
#pragma unroll
  for (int mf = 0; mf < 2; ++mf)
#pragma unroll
    for (int r = 0; r < 4; ++r) {
      float l = lsum[mf][r];
#pragma unroll
      for (int o = 1; o < 16; o <<= 1) l += __shfl_xor(l, o);
      float inv = 1.0f / l;
      size_t cb = ((size_t)(omt + mf) * 96 + h * 8 + (l15 >> 3)) * 128
                + (quad * 4 + r) * 8 + (l15 & 7);
#pragma unroll
      for (int df = 0; df < 4; ++df)
        ctx[cb + df * 256] = f2bf(O[mf][df][r] * inv);
    }
}

// ------------------------------------------------------------------ launch --
extern "C" void kernel_launch(void* const* d_in, const int* in_sizes, int n_in,
                              void* d_out, int out_size, void* d_ws, size_t ws_size,
                              hipStream_t stream) {
  (void)in_sizes; (void)n_in; (void)out_size; (void)ws_size;
  const float* before = (const float*)d_in[0];
  const float* after  = (const float*)d_in[1];
  const float* wqkv   = (const float*)d_in[2];
  const float* lng    = (const float*)d_in[3];
  const float* lnb    = (const float*)d_in[4];
  const float* wproj  = (const float*)d_in[5];
  const float* bproj  = (const float*)d_in[6];
  float* out = (float*)d_out;
  us* ws  = (us*)d_ws;
  us* xbt  = ws;
  us* wqt  = ws + 6291456;
  us* wpt  = ws + 8060928;
  us* qkvr = ws + 8650752;
  us* vtg  = ws + 21233664;
  us* ctx  = ws + 27525120;

  k_convert<<<4224, 256, 0, stream>>>(before, after, wqkv, wproj, ws);
  k_gemm_qkv<<<dim3(64, 18), 256, 0, stream>>>(xbt, wqt, qkvr, vtg, lng, lnb);
  k_attn<<<dim3(96, 8), 256, 0, stream>>>(qkvr, vtg, ctx);
  k_gemm_proj<<<dim3(128, 6), 256, 0, stream>>>(ctx, wpt, out, qkvr, bproj);
}

// Round 10
// 189.630 us; speedup vs baseline: 1.0477x; 1.0477x over previous
//
#include <hip/hip_runtime.h>

// ---------------------------------------------------------------------------
// Fused: qkv-proj + head-LN -> cross-attention (x2) -> proj.
// B=4, N=1024, C=768, H=12, HD=64.  MFMA bf16 16x16x32, f32 accum.
//
// Round-10:
//  * Attention computes S^T = K·Q^T so softmax P stays IN REGISTERS:
//    S^T's C-layout (qrow=lane&15, key=quad*4+reg) is exactly the PV
//    B-operand layout under the key permutation pos={nf1,quad,nf0,r}.
//    V's key dim is emitted in pos-order by gemm_qkv's fused V-epilogue
//    (exact: PV sums over keys).  No P LDS round-trip, no Ps array,
//    l-reduction = 2 shuffles at epilogue, packing = 16 v_perm_b32.
//  * q stored pre-scaled by C1=0.125*log2(e) (softmax exp2 needs no mul);
//    proj residual un-scales with one mul (1/C1).
//  * GEMM: r7-measured-best mainloop (__syncthreads, single-buffer LDS,
//    BK=64, reg prefetch 1).  Fragment-tiled layouts, XCD-aware grids.
//
// ws layout (ushort elements):
//   xbt  @ 0        : tiled [8192 x 768]  (rows 0..4095 before, rest after)
//   wqt  @ 6291456  : tiled [2304 x 768]
//   wpt  @ 8060928  : tiled [768 x 768]
//   qkvr @ 8650752  : tiled [8192 x 1536] post-LN q(*C1),k (192 k-chunks)
//   vtg  @ 21233664 : 96 heads x tiled [64 d x 1024 pos]  (pos-permuted keys)
//   ctx  @ 27525120 : tiled [8192 x 768]
// ---------------------------------------------------------------------------

typedef __bf16 bf16x8 __attribute__((ext_vector_type(8)));
typedef float  f32x4  __attribute__((ext_vector_type(4)));
typedef unsigned int u32x4 __attribute__((ext_vector_type(4)));
typedef unsigned short us;

#define MFMA16(a, b, c) __builtin_amdgcn_mfma_f32_16x16x32_bf16(a, b, c, 0, 0, 0)

#define C1F 0.18033688011112042f     // 0.125 * log2(e)
#define INV_C1F 5.545177444479562f   // 1/C1F

__device__ __forceinline__ us f2bf(float f) {
  unsigned int u = __builtin_bit_cast(unsigned int, f);
  u += 0x7FFFu + ((u >> 16) & 1u);   // RNE
  return (us)(u >> 16);
}
__device__ __forceinline__ float bf2f(us h) {
  unsigned int u = ((unsigned int)h) << 16;
  return __builtin_bit_cast(float, u);
}
__device__ __forceinline__ bf16x8 ld16(const us* p) {
  return __builtin_bit_cast(bf16x8, *(const u32x4*)p);
}
// pack two f32 -> (bf16lo | bf16hi<<16), truncation, 1 v_perm_b32
__device__ __forceinline__ unsigned int pkbf(float lo, float hi) {
  return __builtin_amdgcn_perm(__builtin_bit_cast(unsigned int, hi),
                               __builtin_bit_cast(unsigned int, lo),
                               0x07060302u);
}

// LDS chunk stride: 128 elems payload padded to 136 (272B; 68 words ≡ 4
// mod 32 -> quad-adjacent chunks hit shifted banks).
#define CH 136

// ---------------------------------------------------------------- convert --
// f32 row-major -> bf16 fragment-tiled.  One 16B tiled piece per thread.
__global__ __launch_bounds__(256) void k_convert(
    const float* __restrict__ before, const float* __restrict__ after,
    const float* __restrict__ wqkv, const float* __restrict__ wproj,
    us* __restrict__ ws) {
  int t = blockIdx.x * 256 + threadIdx.x;
  us* dst; int u;
  if (t < 786432)       { u = t;           dst = ws; }
  else if (t < 1007616) { u = t - 786432;  dst = ws + 6291456; }
  else                  { u = t - 1007616; dst = ws + 8060928; }
  int l15 = u & 15, c2 = u >> 4;
  int kc = c2 % 96, mt = c2 / 96;
  int row = mt * 16 + l15;
  const float* srow;
  if (t < 786432)       srow = row < 4096 ? before + (size_t)row * 768
                                          : after + (size_t)(row - 4096) * 768;
  else if (t < 1007616) srow = wqkv + (size_t)row * 768;
  else                  srow = wproj + (size_t)row * 768;
  const float4* s4 = (const float4*)(srow + kc * 8);
  float4 a = s4[0], b = s4[1];
  union { u32x4 v; us s[8]; } o;
  o.s[0] = f2bf(a.x); o.s[1] = f2bf(a.y); o.s[2] = f2bf(a.z); o.s[3] = f2bf(a.w);
  o.s[4] = f2bf(b.x); o.s[5] = f2bf(b.y); o.s[6] = f2bf(b.z); o.s[7] = f2bf(b.w);
  *(u32x4*)(dst + (size_t)c2 * 128 + l15 * 8) = o.v;
}

// -------------------------------------------------------------- gemm main --
// NT GEMM main loop on tiled operands, block tile MT x 128, 4 waves (2x2),
// K=768 (12 x BK=64).  Single-buffer LDS, __syncthreads, reg prefetch 1.
template <int MT>
__device__ __forceinline__ void gemm_mainloop(
    const us* __restrict__ A, const us* __restrict__ B,
    int m0, int n0, us* As, us* Bs, f32x4 (&acc)[MT / 32][4]) {
  constexpr int AJ = MT / 32;
  constexpr int NITER = 12;
  const int tid = threadIdx.x, lane = tid & 63, w = tid >> 6;
  const int quad = lane >> 4, l15 = lane & 15;
  const int wm = (w >> 1) * (MT / 2), wn = (w & 1) * 64;
  u32x4 ra[AJ], rb[4];

  auto load_regs = [&](int k0) {
#pragma unroll
    for (int j = 0; j < AJ; ++j) {
      int u = w * AJ + j;
      ra[j] = *(const u32x4*)(A + ((size_t)((m0 >> 4) + (u >> 1)) * 96
                                   + (k0 >> 3) + (u & 1) * 4) * 128 + lane * 8);
    }
#pragma unroll
    for (int j = 0; j < 4; ++j) {
      int u = w * 4 + j;
      rb[j] = *(const u32x4*)(B + ((size_t)((n0 >> 4) + (u >> 1)) * 96
                                   + (k0 >> 3) + (u & 1) * 4) * 128 + lane * 8);
    }
  };
  auto store_regs = [&]() {
#pragma unroll
    for (int j = 0; j < AJ; ++j) {
      int slot = (w * AJ + j) * 4 + quad;
      *(u32x4*)(As + slot * CH + l15 * 8) = ra[j];
    }
#pragma unroll
    for (int j = 0; j < 4; ++j) {
      int slot = (w * 4 + j) * 4 + quad;
      *(u32x4*)(Bs + slot * CH + l15 * 8) = rb[j];
    }
  };

  load_regs(0);
  store_regs();
  __syncthreads();

#pragma unroll
  for (int it = 0; it < NITER; ++it) {
    if (it + 1 < NITER) load_regs((it + 1) * 64);
#pragma unroll
    for (int ks = 0; ks < 2; ++ks) {
      bf16x8 af[AJ], bfr[4];
#pragma unroll
      for (int mf = 0; mf < AJ; ++mf)
        af[mf] = ld16(As + (((wm >> 4) + mf) * 8 + ks * 4 + quad) * CH + l15 * 8);
#pragma unroll
      for (int nf = 0; nf < 4; ++nf)
        bfr[nf] = ld16(Bs + (((wn >> 4) + nf) * 8 + ks * 4 + quad) * CH + l15 * 8);
#pragma unroll
      for (int mf = 0; mf < AJ; ++mf)
#pragma unroll
        for (int nf = 0; nf < 4; ++nf)
          acc[mf][nf] = MFMA16(af[mf], bfr[nf], acc[mf][nf]);
    }
    __syncthreads();
    if (it + 1 < NITER) {
      store_regs();
      __syncthreads();
    }
  }
}

// --------------------------------------------------------------- gemm qkv --
// grid (64 m-tiles, 18 n-tiles); XCD = m%8 (same-A co-XCD).  Per-head LN
// epilogue.  cols < 768 (q) -> tiled qkvr, pre-scaled by C1; cols in
// [768,1536) (k) -> tiled qkvr; cols >= 1536 (v) -> TRANSPOSED tiled vtg
// with pos-permuted key dim (pos = {nf1, quad, nf0, r} within 64-tile).
__global__ __launch_bounds__(256) void k_gemm_qkv(
    const us* __restrict__ A, const us* __restrict__ B, us* __restrict__ Cqk,
    us* __restrict__ Vg, const float* __restrict__ g, const float* __restrict__ bb) {
  __shared__ us As[64 * CH];
  __shared__ us Bs[64 * CH];
  const int lane = threadIdx.x & 63, w = threadIdx.x >> 6;
  const int quad = lane >> 4, l15 = lane & 15;
  const int m0 = blockIdx.x * 128, n0 = blockIdx.y * 128;
  const int wm = (w >> 1) * 64, wn = (w & 1) * 64;
  f32x4 acc[4][4] = {};
  gemm_mainloop<128>(A, B, m0, n0, As, Bs, acc);

  float gl[4], bl[4];
#pragma unroll
  for (int nf = 0; nf < 4; ++nf) { gl[nf] = g[nf * 16 + l15]; bl[nf] = bb[nf * 16 + l15]; }

  if ((n0 + wn) < 1536) {
    // q/k -> tiled qkvr (192 k-chunks); q additionally scaled by C1
    const float qs = (n0 + wn) < 768 ? C1F : 1.0f;   // wave-uniform
#pragma unroll
    for (int mf = 0; mf < 4; ++mf)
#pragma unroll
      for (int r = 0; r < 4; ++r) {
        float s1 = acc[mf][0][r] + acc[mf][1][r] + acc[mf][2][r] + acc[mf][3][r];
        float s2 = acc[mf][0][r] * acc[mf][0][r] + acc[mf][1][r] * acc[mf][1][r]
                 + acc[mf][2][r] * acc[mf][2][r] + acc[mf][3][r] * acc[mf][3][r];
#pragma unroll
        for (int o = 1; o < 16; o <<= 1) { s1 += __shfl_xor(s1, o); s2 += __shfl_xor(s2, o); }
        float mu = s1 * (1.0f / 64.0f);
        float var = s2 * (1.0f / 64.0f) - mu * mu;
        float sc = rsqrtf(var + 1e-5f);
        size_t cb = ((size_t)(((m0 + wm) >> 4) + mf) * 192 + ((n0 + wn) >> 3)
                     + (l15 >> 3)) * 128 + (quad * 4 + r) * 8 + (l15 & 7);
#pragma unroll
        for (int nf = 0; nf < 4; ++nf)
          Cqk[cb + nf * 256] = f2bf(((acc[mf][nf][r] - mu) * sc * gl[nf] + bl[nf]) * qs);
      }
  } else {
    // v -> transposed tiled vtg[hi][d][pos], pos-permuted key dim
    const int h = ((n0 + wn) - 1536) >> 6;
#pragma unroll
    for (int mf = 0; mf < 4; ++mf) {
      int mrow = m0 + wm + mf * 16;        // 16-aligned token base
      int s = mrow >> 12, b2 = (mrow >> 10) & 3;
      int K0 = mrow & 1023;
      int nfk = (K0 >> 4) & 3;             // key64 bits [5:4]
      us* vb = Vg + (size_t)(s * 48 + b2 * 12 + h) * 65536;
      float vv[4][4];
#pragma unroll
      for (int r = 0; r < 4; ++r) {
        float s1 = acc[mf][0][r] + acc[mf][1][r] + acc[mf][2][r] + acc[mf][3][r];
        float s2 = acc[mf][0][r] * acc[mf][0][r] + acc[mf][1][r] * acc[mf][1][r]
                 + acc[mf][2][r] * acc[mf][2][r] + acc[mf][3][r] * acc[mf][3][r];
#pragma unroll
        for (int o = 1; o < 16; o <<= 1) { s1 += __shfl_xor(s1, o); s2 += __shfl_xor(s2, o); }
        float mu = s1 * (1.0f / 64.0f);
        float var = s2 * (1.0f / 64.0f) - mu * mu;
        float sc = rsqrtf(var + 1e-5f);
#pragma unroll
        for (int nf = 0; nf < 4; ++nf)
          vv[nf][r] = (acc[mf][nf][r] - mu) * sc * gl[nf] + bl[nf];
      }
      // pos = (kt64)*64 + nfk1*32 + quad*8 + nfk0*4 + r  (r contiguous)
      size_t pchunk = ((size_t)(K0 >> 6) << 3) + ((nfk >> 1) << 2) + quad;
      int poff = l15 * 8 + (nfk & 1) * 4;
#pragma unroll
      for (int nf = 0; nf < 4; ++nf) {
        ushort4 o4;
        o4.x = f2bf(vv[nf][0]); o4.y = f2bf(vv[nf][1]);
        o4.z = f2bf(vv[nf][2]); o4.w = f2bf(vv[nf][3]);
        *(ushort4*)(vb + ((size_t)nf * 128 + pchunk) * 128 + poff) = o4;
      }
    }
  }
}

// -------------------------------------------------------------- gemm proj --
// grid (128 m-tiles, 6 n-tiles).  f32 row-major out + bias + untransposed-q
// residual (q stored scaled by C1 -> un-scale with INV_C1F).
__global__ __launch_bounds__(256) void k_gemm_proj(
    const us* __restrict__ A, const us* __restrict__ B, float* __restrict__ C,
    const us* __restrict__ qkvr, const float* __restrict__ bias) {
  __shared__ us As[32 * CH];
  __shared__ us Bs[64 * CH];
  const int lane = threadIdx.x & 63, w = threadIdx.x >> 6;
  const int quad = lane >> 4, l15 = lane & 15;
  const int m0 = blockIdx.x * 64, n0 = blockIdx.y * 128;
  const int wm = (w >> 1) * 32, wn = (w & 1) * 64;
  f32x4 acc[2][4] = {};
  gemm_mainloop<64>(A, B, m0, n0, As, Bs, acc);

  const int cg = (n0 + wn) >> 6;          // wave-uniform column group
  float bl[4];
#pragma unroll
  for (int nf = 0; nf < 4; ++nf) bl[nf] = bias[n0 + wn + nf * 16 + l15];
#pragma unroll
  for (int mf = 0; mf < 2; ++mf)
#pragma unroll
    for (int r = 0; r < 4; ++r) {
      int row = m0 + wm + mf * 16 + quad * 4 + r;
      int hf = row >> 12;                 // 0 -> context_b (q=after), 1 -> context_a
      int m4 = row & 4095;
      int b = m4 >> 10, i = m4 & 1023;
      int j = i * 12 + cg;                // f>>6 where f = i*768+col
      int h = j >> 10, n = j & 1023;      // d = nf*16 + l15
      int qrow = ((hf ^ 1) << 12) + (b << 10) + n;
      size_t rb2 = ((size_t)(qrow >> 4) * 192 + h * 8 + (l15 >> 3)) * 128
                 + (qrow & 15) * 8 + (l15 & 7);
      size_t base = (size_t)row * 768 + n0 + wn + l15;
#pragma unroll
      for (int nf = 0; nf < 4; ++nf)
        C[base + nf * 16] = acc[mf][nf][r] + bl[nf] + bf2f(qkvr[rb2 + nf * 256]) * INV_C1F;
    }
}

// -------------------------------------------------------------- attention --
// grid (96 hi, 8 qt) -> XCD = hi%8 (per-head K/V L2-hot).  K/V double-
// buffered LDS, one __syncthreads per key-tile.  S^T = K·Q^T so P stays in
// registers (C-layout of S^T == PV B-operand layout under the pos key
// permutation baked into vtg).  Static-max softmax (q pre-scaled by C1),
// l-reduction deferred to epilogue (2 shuffles).
__global__ __launch_bounds__(256) void k_attn(const us* __restrict__ qkvr,
                                              const us* __restrict__ vtg,
                                              us* __restrict__ ctx) {
  __shared__ us Ks[2][32 * CH];
  __shared__ us Vt[2][32 * CH];
  const int tid = threadIdx.x, lane = tid & 63, w = tid >> 6;
  const int quad = lane >> 4, l15 = lane & 15;
  const int hi = blockIdx.x, qt = blockIdx.y;
  const int hf = hi / 48, bh = hi - hf * 48;
  const int b = bh / 12, h = bh - (bh / 12) * 12;
  const int ihq = hf ^ 1, ihk = hf;
  const int r0 = qt * 128 + w * 32;
  const int qmt = (ihq * 4096 + b * 1024 + r0) >> 4;
  const int kb16 = (ihk * 4096 + b * 1024) >> 4;
  const us* vbase = vtg + (size_t)(ihk * 48 + b * 12 + h) * 65536;

  // Q fragments resident (B-operand layout = A layout on qrow), pre-scaled
  bf16x8 aq[2][2];
#pragma unroll
  for (int mf = 0; mf < 2; ++mf)
#pragma unroll
    for (int ks = 0; ks < 2; ++ks)
      aq[mf][ks] = ld16(qkvr + ((size_t)(qmt + mf) * 192 + h * 8 + ks * 4 + quad) * 128
                        + l15 * 8);

  u32x4 rk[2], rv[2];
  auto load_kv = [&](int kt) {
#pragma unroll
    for (int j = 0; j < 2; ++j) {
      int u = w * 2 + j;
      rk[j] = *(const u32x4*)(qkvr + ((size_t)(kb16 + kt * 4 + (u >> 1)) * 192
                                      + 96 + h * 8 + (u & 1) * 4) * 128 + lane * 8);
      rv[j] = *(const u32x4*)(vbase + ((size_t)(u >> 1) * 128 + kt * 8
                                       + (u & 1) * 4) * 128 + lane * 8);
    }
  };
  auto store_kv = [&](int buf) {
#pragma unroll
    for (int j = 0; j < 2; ++j) {
      int slot = (w * 2 + j) * 4 + quad;
      *(u32x4*)(Ks[buf] + slot * CH + l15 * 8) = rk[j];
      *(u32x4*)(Vt[buf] + slot * CH + l15 * 8) = rv[j];
    }
  };

  f32x4 O[2][4] = {};           // O^T blocks: [q-block mf][d-block df]
  float lsum[2] = {};           // per-lane (qrow = mf*16 + l15)

  load_kv(0);
  store_kv(0);
  __syncthreads();

  for (int kt = 0; kt < 16; ++kt) {
    const int p = kt & 1;
    if (kt + 1 < 16) load_kv(kt + 1);

    // S^T = K Q^T : D[m=key][n=qrow]
    f32x4 sT[2][4] = {};        // [mf][nf key-block]
#pragma unroll
    for (int ks = 0; ks < 2; ++ks)
#pragma unroll
      for (int nf = 0; nf < 4; ++nf) {
        bf16x8 kf = ld16(Ks[p] + (nf * 8 + ks * 4 + quad) * CH + l15 * 8);
        sT[0][nf] = MFMA16(kf, aq[0][ks], sT[0][nf]);
        sT[1][nf] = MFMA16(kf, aq[1][ks], sT[1][nf]);
      }

    // softmax: p = 2^s (q pre-scaled); pack P into PV B-operand registers
    bf16x8 pf[2][2];            // [mf][k2]
#pragma unroll
    for (int mf = 0; mf < 2; ++mf) {
      float ev[4][4];
#pragma unroll
      for (int nf = 0; nf < 4; ++nf)
#pragma unroll
        for (int r = 0; r < 4; ++r)
          ev[nf][r] = __builtin_amdgcn_exp2f(sT[mf][nf][r]);
      lsum[mf] += ((ev[0][0] + ev[0][1]) + (ev[0][2] + ev[0][3]))
                + ((ev[1][0] + ev[1][1]) + (ev[1][2] + ev[1][3]))
                + ((ev[2][0] + ev[2][1]) + (ev[2][2] + ev[2][3]))
                + ((ev[3][0] + ev[3][1]) + (ev[3][2] + ev[3][3]));
#pragma unroll
      for (int k2 = 0; k2 < 2; ++k2) {
        u32x4 wds;
#pragma unroll
        for (int wd = 0; wd < 4; ++wd)
          wds[wd] = pkbf(ev[k2 * 2 + (wd >> 1)][(wd & 1) * 2],
                         ev[k2 * 2 + (wd >> 1)][(wd & 1) * 2 + 1]);
        pf[mf][k2] = __builtin_bit_cast(bf16x8, wds);
      }
    }

    // O^T += V^T P^T : A = Vt frag, B = pf (registers)
#pragma unroll
    for (int k2 = 0; k2 < 2; ++k2)
#pragma unroll
      for (int df = 0; df < 4; ++df) {
        bf16x8 av = ld16(Vt[p] + (df * 8 + k2 * 4 + quad) * CH + l15 * 8);
        O[0][df] = MFMA16(av, pf[0][k2], O[0][df]);
        O[1][df] = MFMA16(av, pf[1][k2], O[1][df]);
      }

    if (kt + 1 < 16) store_kv(p ^ 1);
    __syncthreads();
  }

  // epilogue: l-reduction over quads, scale, store ctx TILED
  const int mc0 = hf * 256 + b * 64 + qt * 8 + w * 2;   // token>>4 base
#pragma unroll
  for (int mf = 0; mf < 2; ++mf) {
    float l = lsum[mf];
    l += __shfl_xor(l, 16);
    l += __shfl_xor(l, 32);
    float inv = 1.0f / l;
#pragma unroll
    for (int df = 0; df < 4; ++df) {
      ushort4 o4;
      o4.x = f2bf(O[mf][df][0] * inv); o4.y = f2bf(O[mf][df][1] * inv);
      o4.z = f2bf(O[mf][df][2] * inv); o4.w = f2bf(O[mf][df][3] * inv);
      *(ushort4*)(ctx + ((size_t)(mc0 + mf) * 96 + h * 8 + df * 2 + (quad >> 1)) * 128
                  + l15 * 8 + (quad & 1) * 4) = o4;
    }
  }
}

// ------------------------------------------------------------------ launch --
extern "C" void kernel_launch(void* const* d_in, const int* in_sizes, int n_in,
                              void* d_out, int out_size, void* d_ws, size_t ws_size,
                              hipStream_t stream) {
  (void)in_sizes; (void)n_in; (void)out_size; (void)ws_size;
  const float* before = (const float*)d_in[0];
  const float* after  = (const float*)d_in[1];
  const float* wqkv   = (const float*)d_in[2];
  const float* lng    = (const float*)d_in[3];
  const float* lnb    = (const float*)d_in[4];
  const float* wproj  = (const float*)d_in[5];
  const float* bproj  = (const float*)d_in[6];
  float* out = (float*)d_out;
  us* ws  = (us*)d_ws;
  us* xbt  = ws;
  us* wqt  = ws + 6291456;
  us* wpt  = ws + 8060928;
  us* qkvr = ws + 8650752;
  us* vtg  = ws + 21233664;
  us* ctx  = ws + 27525120;

  k_convert<<<4224, 256, 0, stream>>>(before, after, wqkv, wproj, ws);
  k_gemm_qkv<<<dim3(64, 18), 256, 0, stream>>>(xbt, wqt, qkvr, vtg, lng, lnb);
  k_attn<<<dim3(96, 8), 256, 0, stream>>>(qkvr, vtg, ctx);
  k_gemm_proj<<<dim3(128, 6), 256, 0, stream>>>(ctx, wpt, out, qkvr, bproj);
}

// Round 11
// 186.108 us; speedup vs baseline: 1.0675x; 1.0189x over previous
//
#include <hip/hip_runtime.h>

// ---------------------------------------------------------------------------
// Fused: qkv-proj + head-LN -> cross-attention (x2) -> proj.
// B=4, N=1024, C=768, H=12, HD=64.  MFMA bf16 16x16x32, f32 accum.
//
// Round-11:
//  * GEMM prefetch DISTANCE 2 (two register stages): loads for tile it+2
//    issue at iter it; their ds_write waits a full iteration (~600+ cyc)
//    after issue.  Distance-1 (r7-r10) exposed ~300+ cyc of load latency
//    per iteration -> 95% stall at 8 waves/CU.  LDS stays single-buffered
//    (occupancy untouched).
//  * Attention: same distance-2 upgrade on its double-buffered K/V loop
//    (manual 2-step unroll keeps stage indices static).
//  * Everything else identical to r10: S^T in-register-P attention,
//    fragment-tiled layouts, fused V-transpose + LN epilogue, q pre-scaled
//    by C1, XCD-aware grids.
//
// ws layout (ushort elements):
//   xbt  @ 0        : tiled [8192 x 768]  (rows 0..4095 before, rest after)
//   wqt  @ 6291456  : tiled [2304 x 768]
//   wpt  @ 8060928  : tiled [768 x 768]
//   qkvr @ 8650752  : tiled [8192 x 1536] post-LN q(*C1),k (192 k-chunks)
//   vtg  @ 21233664 : 96 heads x tiled [64 d x 1024 pos]  (pos-permuted keys)
//   ctx  @ 27525120 : tiled [8192 x 768]
// ---------------------------------------------------------------------------

typedef __bf16 bf16x8 __attribute__((ext_vector_type(8)));
typedef float  f32x4  __attribute__((ext_vector_type(4)));
typedef unsigned int u32x4 __attribute__((ext_vector_type(4)));
typedef unsigned short us;

#define MFMA16(a, b, c) __builtin_amdgcn_mfma_f32_16x16x32_bf16(a, b, c, 0, 0, 0)

#define C1F 0.18033688011112042f     // 0.125 * log2(e)
#define INV_C1F 5.545177444479562f   // 1/C1F

__device__ __forceinline__ us f2bf(float f) {
  unsigned int u = __builtin_bit_cast(unsigned int, f);
  u += 0x7FFFu + ((u >> 16) & 1u);   // RNE
  return (us)(u >> 16);
}
__device__ __forceinline__ float bf2f(us h) {
  unsigned int u = ((unsigned int)h) << 16;
  return __builtin_bit_cast(float, u);
}
__device__ __forceinline__ bf16x8 ld16(const us* p) {
  return __builtin_bit_cast(bf16x8, *(const u32x4*)p);
}
// pack two f32 -> (bf16lo | bf16hi<<16), truncation, 1 v_perm_b32
__device__ __forceinline__ unsigned int pkbf(float lo, float hi) {
  return __builtin_amdgcn_perm(__builtin_bit_cast(unsigned int, hi),
                               __builtin_bit_cast(unsigned int, lo),
                               0x07060302u);
}

// LDS chunk stride: 128 elems payload padded to 136 (272B; 68 words ≡ 4
// mod 32 -> quad-adjacent chunks hit shifted banks).
#define CH 136

// ---------------------------------------------------------------- convert --
// f32 row-major -> bf16 fragment-tiled.  One 16B tiled piece per thread.
__global__ __launch_bounds__(256) void k_convert(
    const float* __restrict__ before, const float* __restrict__ after,
    const float* __restrict__ wqkv, const float* __restrict__ wproj,
    us* __restrict__ ws) {
  int t = blockIdx.x * 256 + threadIdx.x;
  us* dst; int u;
  if (t < 786432)       { u = t;           dst = ws; }
  else if (t < 1007616) { u = t - 786432;  dst = ws + 6291456; }
  else                  { u = t - 1007616; dst = ws + 8060928; }
  int l15 = u & 15, c2 = u >> 4;
  int kc = c2 % 96, mt = c2 / 96;
  int row = mt * 16 + l15;
  const float* srow;
  if (t < 786432)       srow = row < 4096 ? before + (size_t)row * 768
                                          : after + (size_t)(row - 4096) * 768;
  else if (t < 1007616) srow = wqkv + (size_t)row * 768;
  else                  srow = wproj + (size_t)row * 768;
  const float4* s4 = (const float4*)(srow + kc * 8);
  float4 a = s4[0], b = s4[1];
  union { u32x4 v; us s[8]; } o;
  o.s[0] = f2bf(a.x); o.s[1] = f2bf(a.y); o.s[2] = f2bf(a.z); o.s[3] = f2bf(a.w);
  o.s[4] = f2bf(b.x); o.s[5] = f2bf(b.y); o.s[6] = f2bf(b.z); o.s[7] = f2bf(b.w);
  *(u32x4*)(dst + (size_t)c2 * 128 + l15 * 8) = o.v;
}

// -------------------------------------------------------------- gemm main --
// NT GEMM main loop on tiled operands, block tile MT x 128, 4 waves (2x2),
// K=768 (12 x BK=64).  Single-buffer LDS, __syncthreads, PREFETCH DIST 2.
template <int MT>
__device__ __forceinline__ void gemm_mainloop(
    const us* __restrict__ A, const us* __restrict__ B,
    int m0, int n0, us* As, us* Bs, f32x4 (&acc)[MT / 32][4]) {
  constexpr int AJ = MT / 32;
  constexpr int NITER = 12;
  const int tid = threadIdx.x, lane = tid & 63, w = tid >> 6;
  const int quad = lane >> 4, l15 = lane & 15;
  const int wm = (w >> 1) * (MT / 2), wn = (w & 1) * 64;
  u32x4 ra[2][AJ], rb[2][4];               // two pipeline stages

  auto load_regs = [&](int s, int k0) {
#pragma unroll
    for (int j = 0; j < AJ; ++j) {
      int u = w * AJ + j;
      ra[s][j] = *(const u32x4*)(A + ((size_t)((m0 >> 4) + (u >> 1)) * 96
                                      + (k0 >> 3) + (u & 1) * 4) * 128 + lane * 8);
    }
#pragma unroll
    for (int j = 0; j < 4; ++j) {
      int u = w * 4 + j;
      rb[s][j] = *(const u32x4*)(B + ((size_t)((n0 >> 4) + (u >> 1)) * 96
                                      + (k0 >> 3) + (u & 1) * 4) * 128 + lane * 8);
    }
  };
  auto store_regs = [&](int s) {
#pragma unroll
    for (int j = 0; j < AJ; ++j) {
      int slot = (w * AJ + j) * 4 + quad;
      *(u32x4*)(As + slot * CH + l15 * 8) = ra[s][j];
    }
#pragma unroll
    for (int j = 0; j < 4; ++j) {
      int slot = (w * 4 + j) * 4 + quad;
      *(u32x4*)(Bs + slot * CH + l15 * 8) = rb[s][j];
    }
  };

  load_regs(0, 0);
  load_regs(1, 64);
  store_regs(0);
  __syncthreads();

#pragma unroll
  for (int it = 0; it < NITER; ++it) {
    if (it + 2 < NITER) load_regs(it & 1, (it + 2) * 64);  // dist-2 prefetch
#pragma unroll
    for (int ks = 0; ks < 2; ++ks) {
      bf16x8 af[AJ], bfr[4];
#pragma unroll
      for (int mf = 0; mf < AJ; ++mf)
        af[mf] = ld16(As + (((wm >> 4) + mf) * 8 + ks * 4 + quad) * CH + l15 * 8);
#pragma unroll
      for (int nf = 0; nf < 4; ++nf)
        bfr[nf] = ld16(Bs + (((wn >> 4) + nf) * 8 + ks * 4 + quad) * CH + l15 * 8);
#pragma unroll
      for (int mf = 0; mf < AJ; ++mf)
#pragma unroll
        for (int nf = 0; nf < 4; ++nf)
          acc[mf][nf] = MFMA16(af[mf], bfr[nf], acc[mf][nf]);
    }
    __syncthreads();
    if (it + 1 < NITER) {
      store_regs((it + 1) & 1);            // loaded a full iteration ago
      __syncthreads();
    }
  }
}

// --------------------------------------------------------------- gemm qkv --
// grid (64 m-tiles, 18 n-tiles); XCD = m%8 (same-A co-XCD).  Per-head LN
// epilogue.  cols < 768 (q) -> tiled qkvr, pre-scaled by C1; cols in
// [768,1536) (k) -> tiled qkvr; cols >= 1536 (v) -> TRANSPOSED tiled vtg
// with pos-permuted key dim (pos = {nf1, quad, nf0, r} within 64-tile).
__global__ __launch_bounds__(256) void k_gemm_qkv(
    const us* __restrict__ A, const us* __restrict__ B, us* __restrict__ Cqk,
    us* __restrict__ Vg, const float* __restrict__ g, const float* __restrict__ bb) {
  __shared__ us As[64 * CH];
  __shared__ us Bs[64 * CH];
  const int lane = threadIdx.x & 63, w = threadIdx.x >> 6;
  const int quad = lane >> 4, l15 = lane & 15;
  const int m0 = blockIdx.x * 128, n0 = blockIdx.y * 128;
  const int wm = (w >> 1) * 64, wn = (w & 1) * 64;
  f32x4 acc[4][4] = {};
  gemm_mainloop<128>(A, B, m0, n0, As, Bs, acc);

  float gl[4], bl[4];
#pragma unroll
  for (int nf = 0; nf < 4; ++nf) { gl[nf] = g[nf * 16 + l15]; bl[nf] = bb[nf * 16 + l15]; }

  if ((n0 + wn) < 1536) {
    // q/k -> tiled qkvr (192 k-chunks); q additionally scaled by C1
    const float qs = (n0 + wn) < 768 ? C1F : 1.0f;   // wave-uniform
#pragma unroll
    for (int mf = 0; mf < 4; ++mf)
#pragma unroll
      for (int r = 0; r < 4; ++r) {
        float s1 = acc[mf][0][r] + acc[mf][1][r] + acc[mf][2][r] + acc[mf][3][r];
        float s2 = acc[mf][0][r] * acc[mf][0][r] + acc[mf][1][r] * acc[mf][1][r]
                 + acc[mf][2][r] * acc[mf][2][r] + acc[mf][3][r] * acc[mf][3][r];
#pragma unroll
        for (int o = 1; o < 16; o <<= 1) { s1 += __shfl_xor(s1, o); s2 += __shfl_xor(s2, o); }
        float mu = s1 * (1.0f / 64.0f);
        float var = s2 * (1.0f / 64.0f) - mu * mu;
        float sc = rsqrtf(var + 1e-5f);
        size_t cb = ((size_t)(((m0 + wm) >> 4) + mf) * 192 + ((n0 + wn) >> 3)
                     + (l15 >> 3)) * 128 + (quad * 4 + r) * 8 + (l15 & 7);
#pragma unroll
        for (int nf = 0; nf < 4; ++nf)
          Cqk[cb + nf * 256] = f2bf(((acc[mf][nf][r] - mu) * sc * gl[nf] + bl[nf]) * qs);
      }
  } else {
    // v -> transposed tiled vtg[hi][d][pos], pos-permuted key dim
    const int h = ((n0 + wn) - 1536) >> 6;
#pragma unroll
    for (int mf = 0; mf < 4; ++mf) {
      int mrow = m0 + wm + mf * 16;        // 16-aligned token base
      int s = mrow >> 12, b2 = (mrow >> 10) & 3;
      int K0 = mrow & 1023;
      int nfk = (K0 >> 4) & 3;             // key64 bits [5:4]
      us* vb = Vg + (size_t)(s * 48 + b2 * 12 + h) * 65536;
      float vv[4][4];
#pragma unroll
      for (int r = 0; r < 4; ++r) {
        float s1 = acc[mf][0][r] + acc[mf][1][r] + acc[mf][2][r] + acc[mf][3][r];
        float s2 = acc[mf][0][r] * acc[mf][0][r] + acc[mf][1][r] * acc[mf][1][r]
                 + acc[mf][2][r] * acc[mf][2][r] + acc[mf][3][r] * acc[mf][3][r];
#pragma unroll
        for (int o = 1; o < 16; o <<= 1) { s1 += __shfl_xor(s1, o); s2 += __shfl_xor(s2, o); }
        float mu = s1 * (1.0f / 64.0f);
        float var = s2 * (1.0f / 64.0f) - mu * mu;
        float sc = rsqrtf(var + 1e-5f);
#pragma unroll
        for (int nf = 0; nf < 4; ++nf)
          vv[nf][r] = (acc[mf][nf][r] - mu) * sc * gl[nf] + bl[nf];
      }
      // pos = (kt64)*64 + nfk1*32 + quad*8 + nfk0*4 + r  (r contiguous)
      size_t pchunk = ((size_t)(K0 >> 6) << 3) + ((nfk >> 1) << 2) + quad;
      int poff = l15 * 8 + (nfk & 1) * 4;
#pragma unroll
      for (int nf = 0; nf < 4; ++nf) {
        ushort4 o4;
        o4.x = f2bf(vv[nf][0]); o4.y = f2bf(vv[nf][1]);
        o4.z = f2bf(vv[nf][2]); o4.w = f2bf(vv[nf][3]);
        *(ushort4*)(vb + ((size_t)nf * 128 + pchunk) * 128 + poff) = o4;
      }
    }
  }
}

// -------------------------------------------------------------- gemm proj --
// grid (128 m-tiles, 6 n-tiles).  f32 row-major out + bias + untransposed-q
// residual (q stored scaled by C1 -> un-scale with INV_C1F).
__global__ __launch_bounds__(256) void k_gemm_proj(
    const us* __restrict__ A, const us* __restrict__ B, float* __restrict__ C,
    const us* __restrict__ qkvr, const float* __restrict__ bias) {
  __shared__ us As[32 * CH];
  __shared__ us Bs[64 * CH];
  const int lane = threadIdx.x & 63, w = threadIdx.x >> 6;
  const int quad = lane >> 4, l15 = lane & 15;
  const int m0 = blockIdx.x * 64, n0 = blockIdx.y * 128;
  const int wm = (w >> 1) * 32, wn = (w & 1) * 64;
  f32x4 acc[2][4] = {};
  gemm_mainloop<64>(A, B, m0, n0, As, Bs, acc);

  const int cg = (n0 + wn) >> 6;          // wave-uniform column group
  float bl[4];
#pragma unroll
  for (int nf = 0; nf < 4; ++nf) bl[nf] = bias[n0 + wn + nf * 16 + l15];
#pragma unroll
  for (int mf = 0; mf < 2; ++mf)
#pragma unroll
    for (int r = 0; r < 4; ++r) {
      int row = m0 + wm + mf * 16 + quad * 4 + r;
      int hf = row >> 12;                 // 0 -> context_b (q=after), 1 -> context_a
      int m4 = row & 4095;
      int b = m4 >> 10, i = m4 & 1023;
      int j = i * 12 + cg;                // f>>6 where f = i*768+col
      int h = j >> 10, n = j & 1023;      // d = nf*16 + l15
      int qrow = ((hf ^ 1) << 12) + (b << 10) + n;
      size_t rb2 = ((size_t)(qrow >> 4) * 192 + h * 8 + (l15 >> 3)) * 128
                 + (qrow & 15) * 8 + (l15 & 7);
      size_t base = (size_t)row * 768 + n0 + wn + l15;
#pragma unroll
      for (int nf = 0; nf < 4; ++nf)
        C[base + nf * 16] = acc[mf][nf][r] + bl[nf] + bf2f(qkvr[rb2 + nf * 256]) * INV_C1F;
    }
}

// -------------------------------------------------------------- attention --
// grid (96 hi, 8 qt) -> XCD = hi%8 (per-head K/V L2-hot).  K/V double-
// buffered LDS, one __syncthreads per key-tile, PREFETCH DIST 2 (two reg
// stages; manual 2-step unroll keeps stage indices static).  S^T = K·Q^T so
// P stays in registers (pos key permutation baked into vtg).  Static-max
// softmax (q pre-scaled by C1), l-reduction deferred to epilogue.
__global__ __launch_bounds__(256) void k_attn(const us* __restrict__ qkvr,
                                              const us* __restrict__ vtg,
                                              us* __restrict__ ctx) {
  __shared__ us Ks[2][32 * CH];
  __shared__ us Vt[2][32 * CH];
  const int tid = threadIdx.x, lane = tid & 63, w = tid >> 6;
  const int quad = lane >> 4, l15 = lane & 15;
  const int hi = blockIdx.x, qt = blockIdx.y;
  const int hf = hi / 48, bh = hi - hf * 48;
  const int b = bh / 12, h = bh - (bh / 12) * 12;
  const int ihq = hf ^ 1, ihk = hf;
  const int r0 = qt * 128 + w * 32;
  const int qmt = (ihq * 4096 + b * 1024 + r0) >> 4;
  const int kb16 = (ihk * 4096 + b * 1024) >> 4;
  const us* vbase = vtg + (size_t)(ihk * 48 + b * 12 + h) * 65536;

  // Q fragments resident, pre-scaled by C1
  bf16x8 aq[2][2];
#pragma unroll
  for (int mf = 0; mf < 2; ++mf)
#pragma unroll
    for (int ks = 0; ks < 2; ++ks)
      aq[mf][ks] = ld16(qkvr + ((size_t)(qmt + mf) * 192 + h * 8 + ks * 4 + quad) * 128
                        + l15 * 8);

  u32x4 rk[2][2], rv[2][2];                // two pipeline stages
  auto load_kv = [&](int s, int kt) {
#pragma unroll
    for (int j = 0; j < 2; ++j) {
      int u = w * 2 + j;
      rk[s][j] = *(const u32x4*)(qkvr + ((size_t)(kb16 + kt * 4 + (u >> 1)) * 192
                                         + 96 + h * 8 + (u & 1) * 4) * 128 + lane * 8);
      rv[s][j] = *(const u32x4*)(vbase + ((size_t)(u >> 1) * 128 + kt * 8
                                          + (u & 1) * 4) * 128 + lane * 8);
    }
  };
  auto store_kv = [&](int s, int buf) {
#pragma unroll
    for (int j = 0; j < 2; ++j) {
      int slot = (w * 2 + j) * 4 + quad;
      *(u32x4*)(Ks[buf] + slot * CH + l15 * 8) = rk[s][j];
      *(u32x4*)(Vt[buf] + slot * CH + l15 * 8) = rv[s][j];
    }
  };

  f32x4 O[2][4] = {};           // O^T blocks: [q-block mf][d-block df]
  float lsum[2] = {};           // per-lane (qrow = mf*16 + l15)

  auto step = [&](int kt, int p) {         // p = kt&1 (static at call site)
    if (kt + 2 < 16) load_kv(p, kt + 2);   // dist-2 prefetch

    // S^T = K Q^T : D[m=key][n=qrow]
    f32x4 sT[2][4] = {};
#pragma unroll
    for (int ks = 0; ks < 2; ++ks)
#pragma unroll
      for (int nf = 0; nf < 4; ++nf) {
        bf16x8 kf = ld16(Ks[p] + (nf * 8 + ks * 4 + quad) * CH + l15 * 8);
        sT[0][nf] = MFMA16(kf, aq[0][ks], sT[0][nf]);
        sT[1][nf] = MFMA16(kf, aq[1][ks], sT[1][nf]);
      }

    // softmax: p = 2^s (q pre-scaled); pack P into PV B-operand registers
    bf16x8 pf[2][2];
#pragma unroll
    for (int mf = 0; mf < 2; ++mf) {
      float ev[4][4];
#pragma unroll
      for (int nf = 0; nf < 4; ++nf)
#pragma unroll
        for (int r = 0; r < 4; ++r)
          ev[nf][r] = __builtin_amdgcn_exp2f(sT[mf][nf][r]);
      lsum[mf] += ((ev[0][0] + ev[0][1]) + (ev[0][2] + ev[0][3]))
                + ((ev[1][0] + ev[1][1]) + (ev[1][2] + ev[1][3]))
                + ((ev[2][0] + ev[2][1]) + (ev[2][2] + ev[2][3]))
                + ((ev[3][0] + ev[3][1]) + (ev[3][2] + ev[3][3]));
#pragma unroll
      for (int k2 = 0; k2 < 2; ++k2) {
        u32x4 wds;
#pragma unroll
        for (int wd = 0; wd < 4; ++wd)
          wds[wd] = pkbf(ev[k2 * 2 + (wd >> 1)][(wd & 1) * 2],
                         ev[k2 * 2 + (wd >> 1)][(wd & 1) * 2 + 1]);
        pf[mf][k2] = __builtin_bit_cast(bf16x8, wds);
      }
    }

    // O^T += V^T P^T : A = Vt frag, B = pf (registers)
#pragma unroll
    for (int k2 = 0; k2 < 2; ++k2)
#pragma unroll
      for (int df = 0; df < 4; ++df) {
        bf16x8 av = ld16(Vt[p] + (df * 8 + k2 * 4 + quad) * CH + l15 * 8);
        O[0][df] = MFMA16(av, pf[0][k2], O[0][df]);
        O[1][df] = MFMA16(av, pf[1][k2], O[1][df]);
      }

    if (kt + 1 < 16) store_kv(p ^ 1, p ^ 1);  // stage loaded a full kt ago
    __syncthreads();
  };

  load_kv(0, 0);
  load_kv(1, 1);
  store_kv(0, 0);
  __syncthreads();

  for (int kt = 0; kt < 16; kt += 2) {
    step(kt, 0);
    step(kt + 1, 1);
  }

  // epilogue: l-reduction over quads, scale, store ctx TILED
  const int mc0 = hf * 256 + b * 64 + qt * 8 + w * 2;   // token>>4 base
#pragma unroll
  for (int mf = 0; mf < 2; ++mf) {
    float l = lsum[mf];
    l += __shfl_xor(l, 16);
    l += __shfl_xor(l, 32);
    float inv = 1.0f / l;
#pragma unroll
    for (int df = 0; df < 4; ++df) {
      ushort4 o4;
      o4.x = f2bf(O[mf][df][0] * inv); o4.y = f2bf(O[mf][df][1] * inv);
      o4.z = f2bf(O[mf][df][2] * inv); o4.w = f2bf(O[mf][df][3] * inv);
      *(ushort4*)(ctx + ((size_t)(mc0 + mf) * 96 + h * 8 + df * 2 + (quad >> 1)) * 128
                  + l15 * 8 + (quad & 1) * 4) = o4;
    }
  }
}

// ------------------------------------------------------------------ launch --
extern "C" void kernel_launch(void* const* d_in, const int* in_sizes, int n_in,
                              void* d_out, int out_size, void* d_ws, size_t ws_size,
                              hipStream_t stream) {
  (void)in_sizes; (void)n_in; (void)out_size; (void)ws_size;
  const float* before = (const float*)d_in[0];
  const float* after  = (const float*)d_in[1];
  const float* wqkv   = (const float*)d_in[2];
  const float* lng    = (const float*)d_in[3];
  const float* lnb    = (const float*)d_in[4];
  const float* wproj  = (const float*)d_in[5];
  const float* bproj  = (const float*)d_in[6];
  float* out = (float*)d_out;
  us* ws  = (us*)d_ws;
  us* xbt  = ws;
  us* wqt  = ws + 6291456;
  us* wpt  = ws + 8060928;
  us* qkvr = ws + 8650752;
  us* vtg  = ws + 21233664;
  us* ctx  = ws + 27525120;

  k_convert<<<4224, 256, 0, stream>>>(before, after, wqkv, wproj, ws);
  k_gemm_qkv<<<dim3(64, 18), 256, 0, stream>>>(xbt, wqt, qkvr, vtg, lng, lnb);
  k_attn<<<dim3(96, 8), 256, 0, stream>>>(qkvr, vtg, ctx);
  k_gemm_proj<<<dim3(128, 6), 256, 0, stream>>>(ctx, wpt, out, qkvr, bproj);
}

// Round 12
// 182.744 us; speedup vs baseline: 1.0872x; 1.0184x over previous
//
#include <hip/hip_runtime.h>

// ---------------------------------------------------------------------------
// Fused: qkv-proj + head-LN -> cross-attention (x2) -> proj.
// B=4, N=1024, C=768, H=12, HD=64.  MFMA bf16 16x16x32, f32 accum.
//
// Round-12:
//  * GEMM was LDS-BW-bound (192 KB/CU-iter vs ~112 B/cyc ceiling).  B now
//    goes global->VGPR directly (1KB coalesced tiled frags, L2-resident
//    weights, 2-stage reg pipeline) -- no LDS staging for B at all.
//    A uses DOUBLE-BUFFERED A-only LDS with ONE __syncthreads per iter.
//    LDS traffic per CU-iter: 192 KB -> ~80 KB; barriers 24 -> 13.
//  * Attention unchanged from r11 (S^T in-register-P, dist-2, pos-permuted
//    V).  Fragment-tiled layouts, fused V-transpose + LN epilogue, q
//    pre-scaled by C1, XCD-aware grids.
//
// ws layout (ushort elements):
//   xbt  @ 0        : tiled [8192 x 768]  (rows 0..4095 before, rest after)
//   wqt  @ 6291456  : tiled [2304 x 768]
//   wpt  @ 8060928  : tiled [768 x 768]
//   qkvr @ 8650752  : tiled [8192 x 1536] post-LN q(*C1),k (192 k-chunks)
//   vtg  @ 21233664 : 96 heads x tiled [64 d x 1024 pos]  (pos-permuted keys)
//   ctx  @ 27525120 : tiled [8192 x 768]
// ---------------------------------------------------------------------------

typedef __bf16 bf16x8 __attribute__((ext_vector_type(8)));
typedef float  f32x4  __attribute__((ext_vector_type(4)));
typedef unsigned int u32x4 __attribute__((ext_vector_type(4)));
typedef unsigned short us;

#define MFMA16(a, b, c) __builtin_amdgcn_mfma_f32_16x16x32_bf16(a, b, c, 0, 0, 0)

#define C1F 0.18033688011112042f     // 0.125 * log2(e)
#define INV_C1F 5.545177444479562f   // 1/C1F

__device__ __forceinline__ us f2bf(float f) {
  unsigned int u = __builtin_bit_cast(unsigned int, f);
  u += 0x7FFFu + ((u >> 16) & 1u);   // RNE
  return (us)(u >> 16);
}
__device__ __forceinline__ float bf2f(us h) {
  unsigned int u = ((unsigned int)h) << 16;
  return __builtin_bit_cast(float, u);
}
__device__ __forceinline__ bf16x8 ld16(const us* p) {
  return __builtin_bit_cast(bf16x8, *(const u32x4*)p);
}
// pack two f32 -> (bf16lo | bf16hi<<16), truncation, 1 v_perm_b32
__device__ __forceinline__ unsigned int pkbf(float lo, float hi) {
  return __builtin_amdgcn_perm(__builtin_bit_cast(unsigned int, hi),
                               __builtin_bit_cast(unsigned int, lo),
                               0x07060302u);
}

// LDS chunk stride: 128 elems payload padded to 136 (272B; 68 words ≡ 4
// mod 32 -> quad-adjacent chunks hit shifted banks).
#define CH 136

// ---------------------------------------------------------------- convert --
// f32 row-major -> bf16 fragment-tiled.  One 16B tiled piece per thread.
__global__ __launch_bounds__(256) void k_convert(
    const float* __restrict__ before, const float* __restrict__ after,
    const float* __restrict__ wqkv, const float* __restrict__ wproj,
    us* __restrict__ ws) {
  int t = blockIdx.x * 256 + threadIdx.x;
  us* dst; int u;
  if (t < 786432)       { u = t;           dst = ws; }
  else if (t < 1007616) { u = t - 786432;  dst = ws + 6291456; }
  else                  { u = t - 1007616; dst = ws + 8060928; }
  int l15 = u & 15, c2 = u >> 4;
  int kc = c2 % 96, mt = c2 / 96;
  int row = mt * 16 + l15;
  const float* srow;
  if (t < 786432)       srow = row < 4096 ? before + (size_t)row * 768
                                          : after + (size_t)(row - 4096) * 768;
  else if (t < 1007616) srow = wqkv + (size_t)row * 768;
  else                  srow = wproj + (size_t)row * 768;
  const float4* s4 = (const float4*)(srow + kc * 8);
  float4 a = s4[0], b = s4[1];
  union { u32x4 v; us s[8]; } o;
  o.s[0] = f2bf(a.x); o.s[1] = f2bf(a.y); o.s[2] = f2bf(a.z); o.s[3] = f2bf(a.w);
  o.s[4] = f2bf(b.x); o.s[5] = f2bf(b.y); o.s[6] = f2bf(b.z); o.s[7] = f2bf(b.w);
  *(u32x4*)(dst + (size_t)c2 * 128 + l15 * 8) = o.v;
}

// -------------------------------------------------------------- gemm main --
// NT GEMM main loop, block tile MT x 128, 4 waves (2x2), K=768 (12 x BK=64).
// A: double-buffered LDS (dist-2 reg prefetch), ONE __syncthreads/iter.
// B: DIRECT global->VGPR tiled frags (2-stage pipeline), no LDS.
template <int MT>
__device__ __forceinline__ void gemm_mainloop(
    const us* __restrict__ A, const us* __restrict__ B,
    int m0, int n0, us* As, f32x4 (&acc)[MT / 32][4]) {
  constexpr int AJ = MT / 32;               // A stage regs per thread
  constexpr int BUFC = (MT / 2) * CH;       // elems per A buffer
  constexpr int NITER = 12;
  const int tid = threadIdx.x, lane = tid & 63, w = tid >> 6;
  const int quad = lane >> 4, l15 = lane & 15;
  const int wm = (w >> 1) * (MT / 2), wn = (w & 1) * 64;
  u32x4 ra[2][AJ];
  u32x4 rbf[2][8];                          // B frags [stage][ks*4+nf]

  auto load_a = [&](int s, int k0) {
#pragma unroll
    for (int j = 0; j < AJ; ++j) {
      int u = w * AJ + j;
      ra[s][j] = *(const u32x4*)(A + ((size_t)((m0 >> 4) + (u >> 1)) * 96
                                      + (k0 >> 3) + (u & 1) * 4) * 128 + lane * 8);
    }
  };
  auto store_a = [&](int s, int buf) {
#pragma unroll
    for (int j = 0; j < AJ; ++j) {
      int slot = (w * AJ + j) * 4 + quad;
      *(u32x4*)(As + buf * BUFC + slot * CH + l15 * 8) = ra[s][j];
    }
  };
  auto load_b = [&](int s, int k0) {
#pragma unroll
    for (int ks = 0; ks < 2; ++ks)
#pragma unroll
      for (int nf = 0; nf < 4; ++nf)
        rbf[s][ks * 4 + nf] = *(const u32x4*)(B
            + ((size_t)(((n0 + wn) >> 4) + nf) * 96 + (k0 >> 3) + ks * 4 + quad) * 128
            + l15 * 8);
  };

  load_a(0, 0);
  load_a(1, 64);
  load_b(0, 0);
  store_a(0, 0);
  __syncthreads();

#pragma unroll
  for (int it = 0; it < NITER; ++it) {
    const int p = it & 1;
    if (it + 2 < NITER) load_a(p, (it + 2) * 64);
    if (it + 1 < NITER) load_b(p ^ 1, (it + 1) * 64);
#pragma unroll
    for (int ks = 0; ks < 2; ++ks)
#pragma unroll
      for (int mf = 0; mf < AJ; ++mf) {
        bf16x8 af = ld16(As + p * BUFC + (((wm >> 4) + mf) * 8 + ks * 4 + quad) * CH
                         + l15 * 8);
#pragma unroll
        for (int nf = 0; nf < 4; ++nf)
          acc[mf][nf] = MFMA16(af, __builtin_bit_cast(bf16x8, rbf[p][ks * 4 + nf]),
                               acc[mf][nf]);
      }
    if (it + 1 < NITER) store_a(p ^ 1, p ^ 1);   // other buffer: safe pre-sync
    __syncthreads();
  }
}

// --------------------------------------------------------------- gemm qkv --
// grid (64 m-tiles, 18 n-tiles); XCD = m%8 (same-A co-XCD).  Per-head LN
// epilogue.  cols < 768 (q) -> tiled qkvr, pre-scaled by C1; cols in
// [768,1536) (k) -> tiled qkvr; cols >= 1536 (v) -> TRANSPOSED tiled vtg
// with pos-permuted key dim (pos = {nf1, quad, nf0, r} within 64-tile).
__global__ __launch_bounds__(256) void k_gemm_qkv(
    const us* __restrict__ A, const us* __restrict__ B, us* __restrict__ Cqk,
    us* __restrict__ Vg, const float* __restrict__ g, const float* __restrict__ bb) {
  __shared__ us As[128 * CH];               // 2 buffers x 64 chunks
  const int lane = threadIdx.x & 63, w = threadIdx.x >> 6;
  const int quad = lane >> 4, l15 = lane & 15;
  const int m0 = blockIdx.x * 128, n0 = blockIdx.y * 128;
  const int wm = (w >> 1) * 64, wn = (w & 1) * 64;
  f32x4 acc[4][4] = {};
  gemm_mainloop<128>(A, B, m0, n0, As, acc);

  float gl[4], bl[4];
#pragma unroll
  for (int nf = 0; nf < 4; ++nf) { gl[nf] = g[nf * 16 + l15]; bl[nf] = bb[nf * 16 + l15]; }

  if ((n0 + wn) < 1536) {
    // q/k -> tiled qkvr (192 k-chunks); q additionally scaled by C1
    const float qs = (n0 + wn) < 768 ? C1F : 1.0f;   // wave-uniform
#pragma unroll
    for (int mf = 0; mf < 4; ++mf)
#pragma unroll
      for (int r = 0; r < 4; ++r) {
        float s1 = acc[mf][0][r] + acc[mf][1][r] + acc[mf][2][r] + acc[mf][3][r];
        float s2 = acc[mf][0][r] * acc[mf][0][r] + acc[mf][1][r] * acc[mf][1][r]
                 + acc[mf][2][r] * acc[mf][2][r] + acc[mf][3][r] * acc[mf][3][r];
#pragma unroll
        for (int o = 1; o < 16; o <<= 1) { s1 += __shfl_xor(s1, o); s2 += __shfl_xor(s2, o); }
        float mu = s1 * (1.0f / 64.0f);
        float var = s2 * (1.0f / 64.0f) - mu * mu;
        float sc = rsqrtf(var + 1e-5f);
        size_t cb = ((size_t)(((m0 + wm) >> 4) + mf) * 192 + ((n0 + wn) >> 3)
                     + (l15 >> 3)) * 128 + (quad * 4 + r) * 8 + (l15 & 7);
#pragma unroll
        for (int nf = 0; nf < 4; ++nf)
          Cqk[cb + nf * 256] = f2bf(((acc[mf][nf][r] - mu) * sc * gl[nf] + bl[nf]) * qs);
      }
  } else {
    // v -> transposed tiled vtg[hi][d][pos], pos-permuted key dim
    const int h = ((n0 + wn) - 1536) >> 6;
#pragma unroll
    for (int mf = 0; mf < 4; ++mf) {
      int mrow = m0 + wm + mf * 16;        // 16-aligned token base
      int s = mrow >> 12, b2 = (mrow >> 10) & 3;
      int K0 = mrow & 1023;
      int nfk = (K0 >> 4) & 3;             // key64 bits [5:4]
      us* vb = Vg + (size_t)(s * 48 + b2 * 12 + h) * 65536;
      float vv[4][4];
#pragma unroll
      for (int r = 0; r < 4; ++r) {
        float s1 = acc[mf][0][r] + acc[mf][1][r] + acc[mf][2][r] + acc[mf][3][r];
        float s2 = acc[mf][0][r] * acc[mf][0][r] + acc[mf][1][r] * acc[mf][1][r]
                 + acc[mf][2][r] * acc[mf][2][r] + acc[mf][3][r] * acc[mf][3][r];
#pragma unroll
        for (int o = 1; o < 16; o <<= 1) { s1 += __shfl_xor(s1, o); s2 += __shfl_xor(s2, o); }
        float mu = s1 * (1.0f / 64.0f);
        float var = s2 * (1.0f / 64.0f) - mu * mu;
        float sc = rsqrtf(var + 1e-5f);
#pragma unroll
        for (int nf = 0; nf < 4; ++nf)
          vv[nf][r] = (acc[mf][nf][r] - mu) * sc * gl[nf] + bl[nf];
      }
      // pos = (kt64)*64 + nfk1*32 + quad*8 + nfk0*4 + r  (r contiguous)
      size_t pchunk = ((size_t)(K0 >> 6) << 3) + ((nfk >> 1) << 2) + quad;
      int poff = l15 * 8 + (nfk & 1) * 4;
#pragma unroll
      for (int nf = 0; nf < 4; ++nf) {
        ushort4 o4;
        o4.x = f2bf(vv[nf][0]); o4.y = f2bf(vv[nf][1]);
        o4.z = f2bf(vv[nf][2]); o4.w = f2bf(vv[nf][3]);
        *(ushort4*)(vb + ((size_t)nf * 128 + pchunk) * 128 + poff) = o4;
      }
    }
  }
}

// -------------------------------------------------------------- gemm proj --
// grid (128 m-tiles, 6 n-tiles).  f32 row-major out + bias + untransposed-q
// residual (q stored scaled by C1 -> un-scale with INV_C1F).
__global__ __launch_bounds__(256) void k_gemm_proj(
    const us* __restrict__ A, const us* __restrict__ B, float* __restrict__ C,
    const us* __restrict__ qkvr, const float* __restrict__ bias) {
  __shared__ us As[64 * CH];                // 2 buffers x 32 chunks
  const int lane = threadIdx.x & 63, w = threadIdx.x >> 6;
  const int quad = lane >> 4, l15 = lane & 15;
  const int m0 = blockIdx.x * 64, n0 = blockIdx.y * 128;
  const int wm = (w >> 1) * 32, wn = (w & 1) * 64;
  f32x4 acc[2][4] = {};
  gemm_mainloop<64>(A, B, m0, n0, As, acc);

  const int cg = (n0 + wn) >> 6;          // wave-uniform column group
  float bl[4];
#pragma unroll
  for (int nf = 0; nf < 4; ++nf) bl[nf] = bias[n0 + wn + nf * 16 + l15];
#pragma unroll
  for (int mf = 0; mf < 2; ++mf)
#pragma unroll
    for (int r = 0; r < 4; ++r) {
      int row = m0 + wm + mf * 16 + quad * 4 + r;
      int hf = row >> 12;                 // 0 -> context_b (q=after), 1 -> context_a
      int m4 = row & 4095;
      int b = m4 >> 10, i = m4 & 1023;
      int j = i * 12 + cg;                // f>>6 where f = i*768+col
      int h = j >> 10, n = j & 1023;      // d = nf*16 + l15
      int qrow = ((hf ^ 1) << 12) + (b << 10) + n;
      size_t rb2 = ((size_t)(qrow >> 4) * 192 + h * 8 + (l15 >> 3)) * 128
                 + (qrow & 15) * 8 + (l15 & 7);
      size_t base = (size_t)row * 768 + n0 + wn + l15;
#pragma unroll
      for (int nf = 0; nf < 4; ++nf)
        C[base + nf * 16] = acc[mf][nf][r] + bl[nf] + bf2f(qkvr[rb2 + nf * 256]) * INV_C1F;
    }
}

// -------------------------------------------------------------- attention --
// grid (96 hi, 8 qt) -> XCD = hi%8 (per-head K/V L2-hot).  K/V double-
// buffered LDS, one __syncthreads per key-tile, dist-2 reg prefetch.
// S^T = K·Q^T so P stays in registers (pos key permutation baked into vtg).
// Static-max softmax (q pre-scaled by C1), l-reduction deferred to epilogue.
__global__ __launch_bounds__(256) void k_attn(const us* __restrict__ qkvr,
                                              const us* __restrict__ vtg,
                                              us* __restrict__ ctx) {
  __shared__ us Ks[2][32 * CH];
  __shared__ us Vt[2][32 * CH];
  const int tid = threadIdx.x, lane = tid & 63, w = tid >> 6;
  const int quad = lane >> 4, l15 = lane & 15;
  const int hi = blockIdx.x, qt = blockIdx.y;
  const int hf = hi / 48, bh = hi - hf * 48;
  const int b = bh / 12, h = bh - (bh / 12) * 12;
  const int ihq = hf ^ 1, ihk = hf;
  const int r0 = qt * 128 + w * 32;
  const int qmt = (ihq * 4096 + b * 1024 + r0) >> 4;
  const int kb16 = (ihk * 4096 + b * 1024) >> 4;
  const us* vbase = vtg + (size_t)(ihk * 48 + b * 12 + h) * 65536;

  // Q fragments resident, pre-scaled by C1
  bf16x8 aq[2][2];
#pragma unroll
  for (int mf = 0; mf < 2; ++mf)
#pragma unroll
    for (int ks = 0; ks < 2; ++ks)
      aq[mf][ks] = ld16(qkvr + ((size_t)(qmt + mf) * 192 + h * 8 + ks * 4 + quad) * 128
                        + l15 * 8);

  u32x4 rk[2][2], rv[2][2];                // two pipeline stages
  auto load_kv = [&](int s, int kt) {
#pragma unroll
    for (int j = 0; j < 2; ++j) {
      int u = w * 2 + j;
      rk[s][j] = *(const u32x4*)(qkvr + ((size_t)(kb16 + kt * 4 + (u >> 1)) * 192
                                         + 96 + h * 8 + (u & 1) * 4) * 128 + lane * 8);
      rv[s][j] = *(const u32x4*)(vbase + ((size_t)(u >> 1) * 128 + kt * 8
                                          + (u & 1) * 4) * 128 + lane * 8);
    }
  };
  auto store_kv = [&](int s, int buf) {
#pragma unroll
    for (int j = 0; j < 2; ++j) {
      int slot = (w * 2 + j) * 4 + quad;
      *(u32x4*)(Ks[buf] + slot * CH + l15 * 8) = rk[s][j];
      *(u32x4*)(Vt[buf] + slot * CH + l15 * 8) = rv[s][j];
    }
  };

  f32x4 O[2][4] = {};           // O^T blocks: [q-block mf][d-block df]
  float lsum[2] = {};           // per-lane (qrow = mf*16 + l15)

  auto step = [&](int kt, int p) {         // p = kt&1 (static at call site)
    if (kt + 2 < 16) load_kv(p, kt + 2);   // dist-2 prefetch

    // S^T = K Q^T : D[m=key][n=qrow]
    f32x4 sT[2][4] = {};
#pragma unroll
    for (int ks = 0; ks < 2; ++ks)
#pragma unroll
      for (int nf = 0; nf < 4; ++nf) {
        bf16x8 kf = ld16(Ks[p] + (nf * 8 + ks * 4 + quad) * CH + l15 * 8);
        sT[0][nf] = MFMA16(kf, aq[0][ks], sT[0][nf]);
        sT[1][nf] = MFMA16(kf, aq[1][ks], sT[1][nf]);
      }

    // softmax: p = 2^s (q pre-scaled); pack P into PV B-operand registers
    bf16x8 pf[2][2];
#pragma unroll
    for (int mf = 0; mf < 2; ++mf) {
      float ev[4][4];
#pragma unroll
      for (int nf = 0; nf < 4; ++nf)
#pragma unroll
        for (int r = 0; r < 4; ++r)
          ev[nf][r] = __builtin_amdgcn_exp2f(sT[mf][nf][r]);
      lsum[mf] += ((ev[0][0] + ev[0][1]) + (ev[0][2] + ev[0][3]))
                + ((ev[1][0] + ev[1][1]) + (ev[1][2] + ev[1][3]))
                + ((ev[2][0] + ev[2][1]) + (ev[2][2] + ev[2][3]))
                + ((ev[3][0] + ev[3][1]) + (ev[3][2] + ev[3][3]));
#pragma unroll
      for (int k2 = 0; k2 < 2; ++k2) {
        u32x4 wds;
#pragma unroll
        for (int wd = 0; wd < 4; ++wd)
          wds[wd] = pkbf(ev[k2 * 2 + (wd >> 1)][(wd & 1) * 2],
                         ev[k2 * 2 + (wd >> 1)][(wd & 1) * 2 + 1]);
        pf[mf][k2] = __builtin_bit_cast(bf16x8, wds);
      }
    }

    // O^T += V^T P^T : A = Vt frag, B = pf (registers)
#pragma unroll
    for (int k2 = 0; k2 < 2; ++k2)
#pragma unroll
      for (int df = 0; df < 4; ++df) {
        bf16x8 av = ld16(Vt[p] + (df * 8 + k2 * 4 + quad) * CH + l15 * 8);
        O[0][df] = MFMA16(av, pf[0][k2], O[0][df]);
        O[1][df] = MFMA16(av, pf[1][k2], O[1][df]);
      }

    if (kt + 1 < 16) store_kv(p ^ 1, p ^ 1);  // stage loaded a full kt ago
    __syncthreads();
  };

  load_kv(0, 0);
  load_kv(1, 1);
  store_kv(0, 0);
  __syncthreads();

  for (int kt = 0; kt < 16; kt += 2) {
    step(kt, 0);
    step(kt + 1, 1);
  }

  // epilogue: l-reduction over quads, scale, store ctx TILED
  const int mc0 = hf * 256 + b * 64 + qt * 8 + w * 2;   // token>>4 base
#pragma unroll
  for (int mf = 0; mf < 2; ++mf) {
    float l = lsum[mf];
    l += __shfl_xor(l, 16);
    l += __shfl_xor(l, 32);
    float inv = 1.0f / l;
#pragma unroll
    for (int df = 0; df < 4; ++df) {
      ushort4 o4;
      o4.x = f2bf(O[mf][df][0] * inv); o4.y = f2bf(O[mf][df][1] * inv);
      o4.z = f2bf(O[mf][df][2] * inv); o4.w = f2bf(O[mf][df][3] * inv);
      *(ushort4*)(ctx + ((size_t)(mc0 + mf) * 96 + h * 8 + df * 2 + (quad >> 1)) * 128
                  + l15 * 8 + (quad & 1) * 4) = o4;
    }
  }
}

// ------------------------------------------------------------------ launch --
extern "C" void kernel_launch(void* const* d_in, const int* in_sizes, int n_in,
                              void* d_out, int out_size, void* d_ws, size_t ws_size,
                              hipStream_t stream) {
  (void)in_sizes; (void)n_in; (void)out_size; (void)ws_size;
  const float* before = (const float*)d_in[0];
  const float* after  = (const float*)d_in[1];
  const float* wqkv   = (const float*)d_in[2];
  const float* lng    = (const float*)d_in[3];
  const float* lnb    = (const float*)d_in[4];
  const float* wproj  = (const float*)d_in[5];
  const float* bproj  = (const float*)d_in[6];
  float* out = (float*)d_out;
  us* ws  = (us*)d_ws;
  us* xbt  = ws;
  us* wqt  = ws + 6291456;
  us* wpt  = ws + 8060928;
  us* qkvr = ws + 8650752;
  us* vtg  = ws + 21233664;
  us* ctx  = ws + 27525120;

  k_convert<<<4224, 256, 0, stream>>>(before, after, wqkv, wproj, ws);
  k_gemm_qkv<<<dim3(64, 18), 256, 0, stream>>>(xbt, wqt, qkvr, vtg, lng, lnb);
  k_attn<<<dim3(96, 8), 256, 0, stream>>>(qkvr, vtg, ctx);
  k_gemm_proj<<<dim3(128, 6), 256, 0, stream>>>(ctx, wpt, out, qkvr, bproj);
}